// Round 1
// baseline (362.838 us; speedup 1.0000x reference)
//
#include <hip/hip_runtime.h>
#include <math.h>

#define PDIM 4096
#define PAR  4086
#define CONS 10
#define BATCH 2048
#define QDIM 1024
#define NW   192   // 64 (cw1 cols) + 128 (ow1 cols)

// ---------- e = colmean(measure_proj), deterministic two-stage ----------
__global__ __launch_bounds__(256) void colmean_part_k(const float* __restrict__ mp,
                                                      float* __restrict__ epart) {
    int col = blockIdx.x * 256 + threadIdx.x;   // 16 blocks * 256 = 4096
    int z = blockIdx.y;                         // 32 chunks of 32 rows
    float s = 0.f;
    int r0 = z * 32;
    for (int r = 0; r < 32; ++r) s += mp[(size_t)(r0 + r) * PDIM + col];
    epart[(size_t)z * PDIM + col] = s;
}

__global__ __launch_bounds__(256) void colmean_fin_k(const float* __restrict__ epart,
                                                     float* __restrict__ e) {
    int col = blockIdx.x * 256 + threadIdx.x;
    float s = 0.f;
    for (int z = 0; z < 32; ++z) s += epart[(size_t)z * PDIM + col];
    e[col] = s * (1.0f / QDIM);
}

// ---------- tiled transpose: src [4096 x cols] -> dst [cols x 4096] ----------
__global__ __launch_bounds__(256) void transpose_k(const float* __restrict__ src,
                                                   int cols, float* __restrict__ dst) {
    __shared__ float t[32][33];
    int r0 = blockIdx.x * 32;
    int c0 = blockIdx.y * 32;
    int tx = threadIdx.x & 31, ty = threadIdx.x >> 5;   // 32 x 8
    #pragma unroll
    for (int dy = 0; dy < 32; dy += 8)
        t[ty + dy][tx] = src[(size_t)(r0 + ty + dy) * cols + c0 + tx];
    __syncthreads();
    #pragma unroll
    for (int dy = 0; dy < 32; dy += 8)
        dst[(size_t)(c0 + ty + dy) * PDIM + r0 + tx] = t[tx][ty + dy];
}

// ---------- params0 = tanh(0.7*e + 0.3*enc) ----------
__global__ __launch_bounds__(256) void init_params_k(const float* __restrict__ tp,
                                                     const float* __restrict__ cons,
                                                     const float* __restrict__ e,
                                                     float* __restrict__ pm) {
    int idx = blockIdx.x * 256 + threadIdx.x;   // 32768 blocks -> B*P
    int b = idx >> 12, i = idx & 4095;
    float encv = (i < PAR) ? tp[b * PAR + i] : cons[b * CONS + (i - PAR)];
    pm[idx] = tanhf(0.7f * e[i] + 0.3f * encv);
}

// ---------- GEMM1: Tpart[kz] = P[:, kz*512:(kz+1)*512] @ Wf-chunk ----------
// Wf column j<64 -> cw1[:,j]; j>=64 -> ow1[:,j-64] (read directly, no Wf buffer)
__global__ __launch_bounds__(256) void gemm1_k(const float* __restrict__ Pm,
                                               const float* __restrict__ cw1,
                                               const float* __restrict__ ow1,
                                               float* __restrict__ Tp) {
    __shared__ float As[32][68];   // [k][m], transposed for vector reads
    __shared__ float Bs[32][68];   // [k][n]
    const int m0 = blockIdx.x * 64;
    const int n0 = blockIdx.y * 64;     // 0,64,128
    const int kz = blockIdx.z;          // 8 chunks of 512
    const int t = threadIdx.x;
    const int tn = t & 15, tm = t >> 4;
    const int ra = t >> 2, ca = (t & 3) * 8;
    const int rb = t >> 3, cb = (t & 7) * 8;

    const float* bsrc; int bld, bcol;
    if (n0 == 0) { bsrc = cw1; bld = 64; bcol = 0; }
    else         { bsrc = ow1; bld = 128; bcol = n0 - 64; }

    float acc[4][4] = {};
    for (int kt = 0; kt < 512; kt += 32) {
        const float4* sa = reinterpret_cast<const float4*>(
            Pm + (size_t)(m0 + ra) * PDIM + kz * 512 + kt + ca);
        float4 a0 = sa[0], a1 = sa[1];
        As[ca + 0][ra] = a0.x; As[ca + 1][ra] = a0.y;
        As[ca + 2][ra] = a0.z; As[ca + 3][ra] = a0.w;
        As[ca + 4][ra] = a1.x; As[ca + 5][ra] = a1.y;
        As[ca + 6][ra] = a1.z; As[ca + 7][ra] = a1.w;
        const float4* sb = reinterpret_cast<const float4*>(
            bsrc + (size_t)(kz * 512 + kt + rb) * bld + bcol + cb);
        float4 b0 = sb[0], b1 = sb[1];
        *reinterpret_cast<float4*>(&Bs[rb][cb])     = b0;
        *reinterpret_cast<float4*>(&Bs[rb][cb + 4]) = b1;
        __syncthreads();
        #pragma unroll
        for (int k = 0; k < 32; ++k) {
            float4 av = *reinterpret_cast<const float4*>(&As[k][tm * 4]);
            float4 bv = *reinterpret_cast<const float4*>(&Bs[k][tn * 4]);
            float aa[4] = {av.x, av.y, av.z, av.w};
            float bb[4] = {bv.x, bv.y, bv.z, bv.w};
            #pragma unroll
            for (int i = 0; i < 4; ++i)
                #pragma unroll
                for (int j = 0; j < 4; ++j)
                    acc[i][j] = fmaf(aa[i], bb[j], acc[i][j]);
        }
        __syncthreads();
    }
    float* op = Tp + (size_t)kz * BATCH * NW + (size_t)(m0 + tm * 4) * NW + n0 + tn * 4;
    #pragma unroll
    for (int i = 0; i < 4; ++i)
        #pragma unroll
        for (int j = 0; j < 4; ++j)
            op[i * NW + j] = acc[i][j];
}

// ---------- per-row epilogue: T -> D = [dh1 | dhc] ----------
__global__ __launch_bounds__(128) void epi_k(const float* __restrict__ Tp,
        const float* __restrict__ cb1, const float* __restrict__ cw2,
        const float* __restrict__ cb2, const float* __restrict__ ow1,
        const float* __restrict__ ob1, const float* __restrict__ ow2,
        const float* __restrict__ ob2, const float* __restrict__ ow3,
        float* __restrict__ D) {
    const int b = blockIdx.x;
    const int t = threadIdx.x;
    __shared__ float Ts[NW];
    __shared__ float hc[64], cv[10], h1[128], dh2[64], dh1s[128], dz2[10];

    for (int j = t; j < NW; j += 128) {
        float s = 0.f;
        #pragma unroll
        for (int z = 0; z < 8; ++z)
            s += Tp[(size_t)z * BATCH * NW + (size_t)b * NW + j];
        Ts[j] = s;
    }
    __syncthreads();
    if (t < 64) hc[t] = fmaxf(Ts[t] + cb1[t], 0.f);
    __syncthreads();
    if (t < 10) {
        float s = cb2[t];
        for (int k = 0; k < 64; ++k) s += hc[k] * cw2[k * 10 + t];
        cv[t] = 1.f / (1.f + expf(-s));
    }
    __syncthreads();
    {
        float s = Ts[64 + t] + ob1[t];
        #pragma unroll
        for (int c = 0; c < 10; ++c) s += cv[c] * ow1[(size_t)(4096 + c) * 128 + t];
        h1[t] = fmaxf(s, 0.f);
    }
    __syncthreads();
    if (t < 64) {
        float s = ob2[t];
        for (int j = 0; j < 128; ++j) s += h1[j] * ow2[j * 64 + t];
        dh2[t] = (s > 0.f) ? ow3[t] : 0.f;
    }
    __syncthreads();
    {
        float s = 0.f;
        for (int l = 0; l < 64; ++l) s += dh2[l] * ow2[t * 64 + l];
        float v = (h1[t] > 0.f) ? s : 0.f;
        dh1s[t] = v;
        D[(size_t)b * NW + t] = v;
    }
    __syncthreads();
    if (t < 10) {
        float s = 0.f;
        for (int j = 0; j < 128; ++j) s += dh1s[j] * ow1[(size_t)(4096 + t) * 128 + j];
        float c = cv[t];
        dz2[t] = s * c * (1.f - c);
    }
    __syncthreads();
    if (t < 64) {
        float s = 0.f;
        #pragma unroll
        for (int c = 0; c < 10; ++c) s += dz2[c] * cw2[t * 10 + c];
        D[(size_t)b * NW + 128 + t] = (hc[t] > 0.f) ? s : 0.f;
    }
}

// ---------- GEMM2 + update: P -= 0.01 * (D @ Wb) ----------
__global__ __launch_bounds__(256) void gemm2_k(const float* __restrict__ D,
                                               const float* __restrict__ Wb,
                                               float* __restrict__ Pm) {
    __shared__ float Ds[32][68];
    __shared__ float Ws[32][68];
    const int m0 = blockIdx.x * 64;
    const int n0 = blockIdx.y * 64;
    const int t = threadIdx.x;
    const int tn = t & 15, tm = t >> 4;
    const int ra = t >> 2, ca = (t & 3) * 8;
    const int rb = t >> 3, cb = (t & 7) * 8;

    float acc[4][4] = {};
    for (int kt = 0; kt < NW; kt += 32) {
        const float4* sd = reinterpret_cast<const float4*>(
            D + (size_t)(m0 + ra) * NW + kt + ca);
        float4 a0 = sd[0], a1 = sd[1];
        Ds[ca + 0][ra] = a0.x; Ds[ca + 1][ra] = a0.y;
        Ds[ca + 2][ra] = a0.z; Ds[ca + 3][ra] = a0.w;
        Ds[ca + 4][ra] = a1.x; Ds[ca + 5][ra] = a1.y;
        Ds[ca + 6][ra] = a1.z; Ds[ca + 7][ra] = a1.w;
        const float4* sw = reinterpret_cast<const float4*>(
            Wb + (size_t)(kt + rb) * PDIM + n0 + cb);
        float4 b0 = sw[0], b1 = sw[1];
        *reinterpret_cast<float4*>(&Ws[rb][cb])     = b0;
        *reinterpret_cast<float4*>(&Ws[rb][cb + 4]) = b1;
        __syncthreads();
        #pragma unroll
        for (int k = 0; k < 32; ++k) {
            float4 av = *reinterpret_cast<const float4*>(&Ds[k][tm * 4]);
            float4 bv = *reinterpret_cast<const float4*>(&Ws[k][tn * 4]);
            float aa[4] = {av.x, av.y, av.z, av.w};
            float bb[4] = {bv.x, bv.y, bv.z, bv.w};
            #pragma unroll
            for (int i = 0; i < 4; ++i)
                #pragma unroll
                for (int j = 0; j < 4; ++j)
                    acc[i][j] = fmaf(aa[i], bb[j], acc[i][j]);
        }
        __syncthreads();
    }
    float* pp = Pm + (size_t)(m0 + tm * 4) * PDIM + n0 + tn * 4;
    #pragma unroll
    for (int i = 0; i < 4; ++i)
        #pragma unroll
        for (int j = 0; j < 4; ++j)
            pp[i * PDIM + j] -= 0.01f * acc[i][j];
}

extern "C" void kernel_launch(void* const* d_in, const int* in_sizes, int n_in,
                              void* d_out, int out_size, void* d_ws, size_t ws_size,
                              hipStream_t stream) {
    const float* tp   = (const float*)d_in[0];
    const float* cons = (const float*)d_in[1];
    // d_in[2] transverse_field, d_in[3] coupling: DEAD CODE (annealing is identity)
    const float* mp   = (const float*)d_in[4];
    const float* cw1  = (const float*)d_in[5];
    const float* cb1  = (const float*)d_in[6];
    const float* cw2  = (const float*)d_in[7];
    const float* cb2  = (const float*)d_in[8];
    const float* ow1  = (const float*)d_in[9];
    const float* ob1  = (const float*)d_in[10];
    const float* ow2  = (const float*)d_in[11];
    const float* ob2  = (const float*)d_in[12];
    const float* ow3  = (const float*)d_in[13];
    float* pm = (float*)d_out;

    float* ws    = (float*)d_ws;
    float* e     = ws;                          // 4096
    float* epart = e + 4096;                    // 32*4096
    float* Wb    = epart + 32 * 4096;           // 192*4096
    float* Tp    = Wb + (size_t)NW * PDIM;      // 8*2048*192
    float* Dg    = Tp + (size_t)8 * BATCH * NW; // 2048*192

    colmean_part_k<<<dim3(16, 32), 256, 0, stream>>>(mp, epart);
    colmean_fin_k<<<16, 256, 0, stream>>>(epart, e);
    transpose_k<<<dim3(128, 4), 256, 0, stream>>>(ow1, 128, Wb);                     // rows 0..127 = ow1^T
    transpose_k<<<dim3(128, 2), 256, 0, stream>>>(cw1, 64, Wb + (size_t)128 * PDIM); // rows 128..191 = cw1^T
    init_params_k<<<32768, 256, 0, stream>>>(tp, cons, e, pm);

    for (int s = 0; s < 3; ++s) {
        gemm1_k<<<dim3(32, 3, 8), 256, 0, stream>>>(pm, cw1, ow1, Tp);
        epi_k<<<BATCH, 128, 0, stream>>>(Tp, cb1, cw2, cb2, ow1, ob1, ow2, ob2, ow3, Dg);
        gemm2_k<<<dim3(32, 64), 256, 0, stream>>>(Dg, Wb, pm);
    }
}

// Round 2
// 138.874 us; speedup vs baseline: 2.6127x; 2.6127x over previous
//
#include <hip/hip_runtime.h>
#include <math.h>

#define BATCH 2048
#define PDIM  4096
#define PAR   4086
#define CONS  10
#define NW    192     // 64 (cw1 cols) + 128 (ow1 cols)

typedef __attribute__((ext_vector_type(8))) short bf16x8;
typedef __attribute__((ext_vector_type(4))) float f32x4;

__device__ __forceinline__ unsigned short f2bf(float f) {
    unsigned int u = __float_as_uint(f);
    u += 0x7FFFu + ((u >> 16) & 1u);      // RTNE
    return (unsigned short)(u >> 16);
}

// ---------- e = colmean(measure_proj), deterministic two-stage ----------
__global__ __launch_bounds__(256) void colmean_part_k(const float* __restrict__ mp,
                                                      float* __restrict__ epart) {
    int col = blockIdx.x * 256 + threadIdx.x;   // 16 x 256 = 4096
    int z = blockIdx.y;                         // 32 chunks of 32 rows
    float s = 0.f;
    int r0 = z * 32;
    for (int r = 0; r < 32; ++r) s += mp[(size_t)(r0 + r) * PDIM + col];
    epart[(size_t)z * PDIM + col] = s;
}

__global__ __launch_bounds__(256) void colmean_fin_k(const float* __restrict__ epart,
                                                     float* __restrict__ e) {
    int col = blockIdx.x * 256 + threadIdx.x;
    float s = 0.f;
    for (int z = 0; z < 32; ++z) s += epart[(size_t)z * PDIM + col];
    e[col] = s * (1.0f / 1024.0f);
}

// ---------- WT bf16 [192][4096]: rows 0..63 = cw1^T, 64..191 = ow1^T ----------
__global__ __launch_bounds__(256) void prep_WT_k(const float* __restrict__ cw1,
                                                 const float* __restrict__ ow1,
                                                 unsigned short* __restrict__ WT) {
    __shared__ float tile[64][33];
    int k0 = blockIdx.x * 64, j0 = blockIdx.y * 32;
    const float* src; int lds_, jb;
    if (j0 < 64) { src = cw1; lds_ = 64;  jb = j0; }
    else         { src = ow1; lds_ = 128; jb = j0 - 64; }
    int t = threadIdx.x;
    int jl = t & 31, kl0 = t >> 5;
    for (int kk = 0; kk < 64; kk += 8)
        tile[kk + kl0][jl] = src[(size_t)(k0 + kk + kl0) * lds_ + jb + jl];
    __syncthreads();
    int kl = t & 63, jl0 = t >> 6;
    for (int jj = 0; jj < 32; jj += 4)
        WT[(size_t)(j0 + jj + jl0) * PDIM + k0 + kl] = f2bf(tile[kl][jj + jl0]);
}

// ---------- Wcat bf16 [4096][192]: cols 0..127 = ow1 row, 128..191 = cw1 row ----------
__global__ __launch_bounds__(256) void prep_Wcat_k(const float* __restrict__ cw1,
                                                   const float* __restrict__ ow1,
                                                   unsigned short* __restrict__ Wcat) {
    int idx = blockIdx.x * 256 + threadIdx.x;   // 3072 blocks -> 786432
    int n = idx / NW, j = idx % NW;
    float v = (j < 128) ? ow1[(size_t)n * 128 + j] : cw1[(size_t)n * 64 + (j - 128)];
    Wcat[idx] = f2bf(v);
}

// ---------- params0 = tanh(0.7*e + 0.3*enc), f32 -> d_out ----------
__global__ __launch_bounds__(256) void init_params_k(const float* __restrict__ tp,
                                                     const float* __restrict__ cons,
                                                     const float* __restrict__ e,
                                                     float* __restrict__ pm) {
    int idx = blockIdx.x * 256 + threadIdx.x;   // 8192*256 = 2M, 4 elems each
    int b = idx >> 10, i4 = idx & 1023;
    int col = i4 * 4;
    float4 ev = *reinterpret_cast<const float4*>(e + col);
    float evs[4] = {ev.x, ev.y, ev.z, ev.w};
    float o[4];
    #pragma unroll
    for (int j = 0; j < 4; ++j) {
        int i = col + j;
        float encv = (i < PAR) ? tp[(size_t)b * PAR + i] : cons[b * CONS + (i - PAR)];
        o[j] = tanhf(0.7f * evs[j] + 0.3f * encv);
    }
    *reinterpret_cast<float4*>(pm + ((size_t)b << 12) + col) = make_float4(o[0], o[1], o[2], o[3]);
}

// ---------- MFMA split-K GEMM: parts[kz] = A[M][4096] @ WT-like-Bt  ----------
// A: f32 (converted in staging) or bf16. Bt bf16 [N][4096]. out parts [8][M][192].
template<bool AF32>
__global__ __launch_bounds__(256) void gemm_parts_k(const void* __restrict__ Av,
                                                    const unsigned short* __restrict__ Bt,
                                                    float* __restrict__ parts, int M) {
    __shared__ unsigned short As[64][72];
    __shared__ unsigned short Bs[64][72];
    const int m0 = blockIdx.x * 64;
    const int n0 = blockIdx.y * 64;
    const int kz = blockIdx.z;                  // 8 chunks of 512
    const int t = threadIdx.x;
    const int w = t >> 6, l = t & 63;
    const int lr = l & 15, lk = (l >> 4) * 8;

    f32x4 acc[4];
    #pragma unroll
    for (int nf = 0; nf < 4; ++nf) acc[nf] = (f32x4){0.f, 0.f, 0.f, 0.f};

    for (int kt = 0; kt < 512; kt += 64) {
        const int kbase = kz * 512 + kt;
        if (AF32) {
            const float* A = (const float*)Av;
            #pragma unroll
            for (int c = 0; c < 4; ++c) {
                int ch = t + c * 256;           // 0..1023
                int row = ch >> 4, col4 = (ch & 15) * 4;
                float4 v = *reinterpret_cast<const float4*>(
                    A + (size_t)(m0 + row) * PDIM + kbase + col4);
                unsigned int p0 = (unsigned int)f2bf(v.x) | ((unsigned int)f2bf(v.y) << 16);
                unsigned int p1 = (unsigned int)f2bf(v.z) | ((unsigned int)f2bf(v.w) << 16);
                *reinterpret_cast<uint2*>(&As[row][col4]) = make_uint2(p0, p1);
            }
        } else {
            const unsigned short* A = (const unsigned short*)Av;
            #pragma unroll
            for (int c = 0; c < 2; ++c) {
                int ch = t + c * 256;           // 0..511
                int row = ch >> 3, col8 = (ch & 7) * 8;
                *reinterpret_cast<float4*>(&As[row][col8]) =
                    *reinterpret_cast<const float4*>(A + (size_t)(m0 + row) * PDIM + kbase + col8);
            }
        }
        #pragma unroll
        for (int c = 0; c < 2; ++c) {
            int ch = t + c * 256;
            int row = ch >> 3, col8 = (ch & 7) * 8;
            *reinterpret_cast<float4*>(&Bs[row][col8]) =
                *reinterpret_cast<const float4*>(Bt + (size_t)(n0 + row) * PDIM + kbase + col8);
        }
        __syncthreads();
        #pragma unroll
        for (int h = 0; h < 2; ++h) {
            bf16x8 a = *reinterpret_cast<const bf16x8*>(&As[w * 16 + lr][h * 32 + lk]);
            #pragma unroll
            for (int nf = 0; nf < 4; ++nf) {
                bf16x8 b = *reinterpret_cast<const bf16x8*>(&Bs[nf * 16 + lr][h * 32 + lk]);
                acc[nf] = __builtin_amdgcn_mfma_f32_16x16x32_bf16(a, b, acc[nf], 0, 0, 0);
            }
        }
        __syncthreads();
    }
    float* op = parts + (size_t)kz * M * NW + (size_t)(m0 + w * 16 + (l >> 4) * 4) * NW + n0;
    #pragma unroll
    for (int nf = 0; nf < 4; ++nf)
        #pragma unroll
        for (int r = 0; r < 4; ++r)
            op[(size_t)r * NW + nf * 16 + lr] = acc[nf][r];
}

// ---------- reduce split-K parts ----------
__global__ __launch_bounds__(256) void reduce_T_k(const float* __restrict__ parts,
                                                  float* __restrict__ T) {
    int i = blockIdx.x * 256 + threadIdx.x;     // 1536 blocks -> 393216
    float s = 0.f;
    #pragma unroll
    for (int z = 0; z < 8; ++z) s += parts[(size_t)z * BATCH * NW + i];
    T[i] = s;
}

__global__ __launch_bounds__(256) void reduce_gram_k(const float* __restrict__ gpart,
                                                     unsigned short* __restrict__ gram) {
    int i = blockIdx.x * 256 + threadIdx.x;     // 144 blocks -> 36864
    float s = 0.f;
    #pragma unroll
    for (int z = 0; z < 8; ++z) s += gpart[(size_t)z * NW * NW + i];
    gram[i] = f2bf(s);
}

// ---------- MFMA K=192 GEMM with rmw: out -= 0.01 * (A_bf @ Bt_bf^T) ----------
__global__ __launch_bounds__(256) void gemm_upd_k(const unsigned short* __restrict__ A,
                                                  const unsigned short* __restrict__ Bt,
                                                  float* __restrict__ out, int ldout) {
    __shared__ unsigned short As[64][72];
    __shared__ unsigned short Bs[64][72];
    const int m0 = blockIdx.x * 64;
    const int n0 = blockIdx.y * 64;
    const int t = threadIdx.x;
    const int w = t >> 6, l = t & 63;
    const int lr = l & 15, lk = (l >> 4) * 8;

    f32x4 acc[4];
    #pragma unroll
    for (int nf = 0; nf < 4; ++nf) acc[nf] = (f32x4){0.f, 0.f, 0.f, 0.f};

    for (int kt = 0; kt < NW; kt += 64) {
        #pragma unroll
        for (int c = 0; c < 2; ++c) {
            int ch = t + c * 256;
            int row = ch >> 3, col8 = (ch & 7) * 8;
            *reinterpret_cast<float4*>(&As[row][col8]) =
                *reinterpret_cast<const float4*>(A + (size_t)(m0 + row) * NW + kt + col8);
            *reinterpret_cast<float4*>(&Bs[row][col8]) =
                *reinterpret_cast<const float4*>(Bt + (size_t)(n0 + row) * NW + kt + col8);
        }
        __syncthreads();
        #pragma unroll
        for (int h = 0; h < 2; ++h) {
            bf16x8 a = *reinterpret_cast<const bf16x8*>(&As[w * 16 + lr][h * 32 + lk]);
            #pragma unroll
            for (int nf = 0; nf < 4; ++nf) {
                bf16x8 b = *reinterpret_cast<const bf16x8*>(&Bs[nf * 16 + lr][h * 32 + lk]);
                acc[nf] = __builtin_amdgcn_mfma_f32_16x16x32_bf16(a, b, acc[nf], 0, 0, 0);
            }
        }
        __syncthreads();
    }
    float* op = out + (size_t)(m0 + w * 16 + (l >> 4) * 4) * ldout + n0;
    #pragma unroll
    for (int nf = 0; nf < 4; ++nf)
        #pragma unroll
        for (int r = 0; r < 4; ++r)
            op[(size_t)r * ldout + nf * 16 + lr] -= 0.01f * acc[nf][r];
}

// ---------- per-row epilogue: T -> D; Drot=[dhc|dh1] bf16; Dsum f32; Dsumbf ----------
__global__ __launch_bounds__(128) void epi_k(const float* __restrict__ T,
        const float* __restrict__ cb1, const float* __restrict__ cw2,
        const float* __restrict__ cb2, const float* __restrict__ ow1,
        const float* __restrict__ ob1, const float* __restrict__ ow2,
        const float* __restrict__ ob2, const float* __restrict__ ow3,
        int step, float* __restrict__ Dsum, unsigned short* __restrict__ Drot,
        unsigned short* __restrict__ Dsbf) {
    const int b = blockIdx.x;
    const int t = threadIdx.x;
    __shared__ float Ts[NW];
    __shared__ float hc[64], cv[10], h1[128], dh2[64], dh1s[128], dz2[10];

    for (int j = t; j < NW; j += 128) Ts[j] = T[(size_t)b * NW + j];
    __syncthreads();
    if (t < 64) hc[t] = fmaxf(Ts[t] + cb1[t], 0.f);
    __syncthreads();
    if (t < 10) {
        float s = cb2[t];
        for (int k = 0; k < 64; ++k) s += hc[k] * cw2[k * 10 + t];
        cv[t] = 1.f / (1.f + expf(-s));
    }
    __syncthreads();
    {
        float s = Ts[64 + t] + ob1[t];
        #pragma unroll
        for (int c = 0; c < 10; ++c) s += cv[c] * ow1[(size_t)(4096 + c) * 128 + t];
        h1[t] = fmaxf(s, 0.f);
    }
    __syncthreads();
    if (t < 64) {
        float s = ob2[t];
        for (int j = 0; j < 128; ++j) s += h1[j] * ow2[j * 64 + t];
        dh2[t] = (s > 0.f) ? ow3[t] : 0.f;
    }
    __syncthreads();
    {
        float s = 0.f;
        for (int l = 0; l < 64; ++l) s += dh2[l] * ow2[t * 64 + l];
        float v = (h1[t] > 0.f) ? s : 0.f;
        dh1s[t] = v;
        float ns = (step == 0) ? v : (Dsum[(size_t)b * NW + t] + v);
        Dsum[(size_t)b * NW + t] = ns;
        if (step < 2) Drot[(size_t)b * NW + 64 + t] = f2bf(v);
        else          Dsbf[(size_t)b * NW + t] = f2bf(ns);
    }
    __syncthreads();
    if (t < 10) {
        float s = 0.f;
        for (int j = 0; j < 128; ++j) s += dh1s[j] * ow1[(size_t)(4096 + t) * 128 + j];
        float c = cv[t];
        dz2[t] = s * c * (1.f - c);
    }
    __syncthreads();
    if (t < 64) {
        float s = 0.f;
        #pragma unroll
        for (int c = 0; c < 10; ++c) s += dz2[c] * cw2[t * 10 + c];
        float w2 = (hc[t] > 0.f) ? s : 0.f;
        float ns = (step == 0) ? w2 : (Dsum[(size_t)b * NW + 128 + t] + w2);
        Dsum[(size_t)b * NW + 128 + t] = ns;
        if (step < 2) Drot[(size_t)b * NW + t] = f2bf(w2);
        else          Dsbf[(size_t)b * NW + 128 + t] = f2bf(ns);
    }
}

extern "C" void kernel_launch(void* const* d_in, const int* in_sizes, int n_in,
                              void* d_out, int out_size, void* d_ws, size_t ws_size,
                              hipStream_t stream) {
    const float* tp   = (const float*)d_in[0];
    const float* cons = (const float*)d_in[1];
    // d_in[2] transverse_field, d_in[3] coupling: DEAD CODE (annealing is identity)
    const float* mp   = (const float*)d_in[4];
    const float* cw1  = (const float*)d_in[5];
    const float* cb1  = (const float*)d_in[6];
    const float* cw2  = (const float*)d_in[7];
    const float* cb2  = (const float*)d_in[8];
    const float* ow1  = (const float*)d_in[9];
    const float* ob1  = (const float*)d_in[10];
    const float* ow2  = (const float*)d_in[11];
    const float* ob2  = (const float*)d_in[12];
    const float* ow3  = (const float*)d_in[13];
    float* pm = (float*)d_out;

    float* f = (float*)d_ws;
    float* e      = f;  f += 4096;
    float* epart  = f;  f += 32 * 4096;
    float* T      = f;  f += BATCH * NW;
    float* Dsum   = f;  f += BATCH * NW;
    float* Gpart  = f;  f += 8 * NW * NW;
    float* Tparts = f;  f += 8 * BATCH * NW;
    unsigned short* u = (unsigned short*)f;
    unsigned short* WT   = u;  u += NW * PDIM;
    unsigned short* Wcat = u;  u += PDIM * NW;
    unsigned short* Gram = u;  u += NW * NW;
    unsigned short* Drot = u;  u += BATCH * NW;
    unsigned short* Dsbf = u;

    colmean_part_k<<<dim3(16, 32), 256, 0, stream>>>(mp, epart);
    colmean_fin_k<<<16, 256, 0, stream>>>(epart, e);
    prep_WT_k<<<dim3(64, 6), 256, 0, stream>>>(cw1, ow1, WT);
    prep_Wcat_k<<<3072, 256, 0, stream>>>(cw1, ow1, Wcat);
    init_params_k<<<8192, 256, 0, stream>>>(tp, cons, e, pm);

    // Gram = WT @ WT^T (symmetric, bf16)
    gemm_parts_k<false><<<dim3(3, 3, 8), 256, 0, stream>>>(WT, WT, Gpart, NW);
    reduce_gram_k<<<144, 256, 0, stream>>>(Gpart, Gram);

    // T = P0 @ Wf  (the only big K=4096 GEMM)
    gemm_parts_k<true><<<dim3(32, 3, 8), 256, 0, stream>>>(pm, WT, Tparts, BATCH);
    reduce_T_k<<<1536, 256, 0, stream>>>(Tparts, T);

    for (int s = 0; s < 3; ++s) {
        epi_k<<<BATCH, 128, 0, stream>>>(T, cb1, cw2, cb2, ow1, ob1, ow2, ob2, ow3,
                                         s, Dsum, Drot, Dsbf);
        if (s < 2)
            gemm_upd_k<<<dim3(32, 3), 256, 0, stream>>>(Drot, Gram, T, NW);
    }
    // P = P0 - 0.01 * Dsum @ Wb  (the only big N=4096 GEMM)
    gemm_upd_k<<<dim3(32, 64), 256, 0, stream>>>(Dsbf, Wcat, pm, PDIM);
}